// Round 3
// baseline (505.624 us; speedup 1.0000x reference)
//
#include <hip/hip_runtime.h>
#include <cstdint>
#include <cstddef>
#include <cmath>

// ---------------------------------------------------------------------------
// DotProductAttention: out = softmax_causal((x@Q/32) @ (x@K)^T) @ (x@V)
//   B=4, S=4096, D=1024, fp32 in/out, bf16 MFMA compute.
// R8 == R7 resubmit (R7 bench died with a container-level infra error before
// producing results; kernel re-audited: barrier sequence uniform, vmcnt
// invariant proven per-thread, 128 KB static LDS legal on gfx950, no spills
// at 256-VGPR budget).
// R7 changes vs R6 (505 us):
//   - All big uniform GEMMs (projQK, projV, QK^T) move to gemm8_bt: 256x256
//     tile, 512 threads (8 waves 2Mx4N, wave tile 128x64), 128 KB LDS,
//     8-phase counted-vmcnt schedule (T3+T4+T5):
//       per K-tile(64) 4 phases = (kp in {0,1}) x (C-row-half ch in {0,1});
//       each phase: {ds_read frags || stage ONE half-slot of next tile
//       (2x global_load_lds) -> s_barrier -> setprio(1) 16 MFMA setprio(0)
//       -> [vmcnt(4) at phases 2,4] -> s_barrier}.
//     vmcnt(4) leaves the 2 newest stage-ops (4 loads) in flight across
//     barriers (never drains; in-order completion per m135 makes the
//     oldest-landed guarantee architectural). Slot map per K-tile:
//     A-kp0, B-kp0 staged at phases 1,2 (guarded by prev P4 vmcnt);
//     A-kp1, B-kp1 at phases 3,4 (guarded by P2 vmcnt). Last-tile prefetch
//     clamps k to a dead re-load so the count invariant holds uniformly.
//   - Same zero-conflict XOR swizzle as R5/R6 (global-side col8 ^= (row>>1)&3,
//     read-side swq), measured SQ_LDS_BANK_CONFLICT == 0.
//   - PV keeps the R6 balanced 4-wave BM=128 kernel (256^2 causal PV at
//     1 block/CU would be 16:1 imbalanced; 8-phase can't win there yet).
// Workspace map (224 MB):
//   [0,64)   QKx bf16 [B*S][2048]  (Qx=+0, Kx=+1024, ld 2048)
//   [64,96)  Vxt bf16 [B][D][S]
//   [96,224) Sb bf16 [B][S][S]  -- early-phase reuse (all dead before Sb):
//       Vtmp@96 (32M), XB@128 (32M), WTqk@160 (4M), WTv@164 (2M)
// ---------------------------------------------------------------------------

typedef unsigned short u16;
typedef __bf16  bf16x8 __attribute__((ext_vector_type(8)));
typedef float   f32x4  __attribute__((ext_vector_type(4)));
typedef unsigned short u16x4 __attribute__((ext_vector_type(4)));

typedef __attribute__((address_space(1))) void gvoid;
typedef __attribute__((address_space(3))) void lvoid;

__device__ __forceinline__ u16 f2bf(float f) {
  union { float f; unsigned u; } v; v.f = f;
  unsigned u = v.u;
  u += 0x7FFFu + ((u >> 16) & 1u);   // round-to-nearest-even
  return (u16)(u >> 16);
}
__device__ __forceinline__ float bf2f(u16 h) {
  union { unsigned u; float f; } v; v.u = ((unsigned)h) << 16;
  return v.f;
}
__device__ __forceinline__ void async16(const void* g, void* l) {
  __builtin_amdgcn_global_load_lds((gvoid*)(void*)g, (lvoid*)l, 16, 0, 0);
}

// --------------------------- elementwise convert ---------------------------
__global__ void __launch_bounds__(256) cvt_f32_bf16(const float4* __restrict__ in,
                                                    u16* __restrict__ out, int n4) {
  int i = blockIdx.x * 256 + threadIdx.x;
  if (i >= n4) return;
  float4 v = in[i];
  u16x4 o = { f2bf(v.x), f2bf(v.y), f2bf(v.z), f2bf(v.w) };
  *(u16x4*)(out + 4 * (size_t)i) = o;
}

// ------------------------------- transpose ---------------------------------
__device__ __forceinline__ u16 to_bfs(float v, float s) { return f2bf(v * s); }
__device__ __forceinline__ u16 to_bfs(u16 v, float)     { return v; }

template <typename TIN>
__global__ void __launch_bounds__(256) transpose_to_bf16(
    const TIN* __restrict__ in, u16* __restrict__ out,
    int rows, int cols, long inStride, long outStride, float scale) {
  __shared__ u16 t[64][68];                 // stride 136B -> 2-way alias (free)
  int rt = blockIdx.x * 64, ct = blockIdx.y * 64;
  long ib = (long)blockIdx.z * inStride, ob = (long)blockIdx.z * outStride;
  int tx = threadIdx.x & 63, ty = threadIdx.x >> 6;
#pragma unroll
  for (int r = ty; r < 64; r += 4)
    t[r][tx] = to_bfs(in[ib + (long)(rt + r) * cols + ct + tx], scale);
  __syncthreads();
#pragma unroll
  for (int r = ty; r < 64; r += 4)
    out[ob + (long)(ct + r) * rows + rt + tx] = t[tx][r];
}

// --------------------- 8-phase 256x256 GEMM (gemm8_bt) ---------------------
// C[m][n] = alpha * sum_k A[m][k]*Bt[n][k]; bf16 row-major; K mult of 128.
// 512 threads = 8 waves (2M x 4N); wave tile 128x64; acc[8][4] 16x16x32.
// LDS: As/Bs[2 buf][2 kp][256 rows][32 k] = 128 KB total, 1 block/CU.
// TRI: full-tile lower-triangle grid, bid -> (m, n<=m), C(m)=m(m+1)/2.

#define G8_BAR()  __builtin_amdgcn_s_barrier()
#define G8_VMC4() asm volatile("s_waitcnt vmcnt(4)" ::: "memory")
#define G8_VMC0() asm volatile("s_waitcnt vmcnt(0)" ::: "memory")

#define G8_STAGE_A(bn, kp, kb) do { \
    async16(Ag + (kb) + a0, (void*)&As[bn][kp][l0]); \
    async16(Ag + (kb) + a1, (void*)&As[bn][kp][l1]); } while (0)
#define G8_STAGE_B(bn, kp, kb) do { \
    async16(Bg + (kb) + b0, (void*)&Bs[bn][kp][l0]); \
    async16(Bg + (kb) + b1, (void*)&Bs[bn][kp][l1]); } while (0)

#define G8_LDA(bc, kp, ch) do { _Pragma("unroll") \
    for (int u_ = 0; u_ < 4; ++u_) \
      af[u_] = *(const bf16x8*)&As[bc][kp][(wm * 128 + (ch) * 64 + u_ * 16 + lr) * 32 + swq]; \
  } while (0)
#define G8_LDB(bc, kp) do { _Pragma("unroll") \
    for (int j_ = 0; j_ < 4; ++j_) \
      bf[j_] = *(const bf16x8*)&Bs[bc][kp][(wn * 64 + j_ * 16 + lr) * 32 + swq]; \
  } while (0)

#define G8_MFMA(ch) do { \
    __builtin_amdgcn_s_setprio(1); \
    _Pragma("unroll") for (int u_ = 0; u_ < 4; ++u_) \
      _Pragma("unroll") for (int j_ = 0; j_ < 4; ++j_) \
        acc[(ch) * 4 + u_][j_] = __builtin_amdgcn_mfma_f32_16x16x32_bf16( \
            af[u_], bf[j_], acc[(ch) * 4 + u_][j_], 0, 0, 0); \
    __builtin_amdgcn_s_setprio(0); } while (0)

// one K-tile (64) from buffer bc; prefetch next tile's half-slots into bn
#define G8_TILE(bc, bn, kt, kn) do { \
    bf16x8 af[4], bf[4]; \
    /* P1: kp0, C rows 0-63 */ \
    G8_LDB(bc, 0); G8_LDA(bc, 0, 0); \
    G8_STAGE_A(bn, 0, (kn)); \
    G8_BAR(); G8_MFMA(0); G8_BAR(); \
    /* P2: kp0, C rows 64-127 */ \
    G8_LDA(bc, 0, 1); \
    G8_STAGE_B(bn, 0, (kn)); \
    G8_BAR(); G8_MFMA(1); G8_VMC4(); G8_BAR(); \
    /* P3: kp1, C rows 0-63 */ \
    G8_LDB(bc, 1); G8_LDA(bc, 1, 0); \
    G8_STAGE_A(bn, 1, (kn) + 32); \
    G8_BAR(); G8_MFMA(0); G8_BAR(); \
    /* P4: kp1, C rows 64-127 */ \
    G8_LDA(bc, 1, 1); \
    G8_STAGE_B(bn, 1, (kn) + 32); \
    G8_BAR(); G8_MFMA(1); G8_VMC4(); G8_BAR(); } while (0)

template <bool OUTF32, bool TRI>
__global__ void __launch_bounds__(512, 2) gemm8_bt(
    const u16* __restrict__ A, const u16* __restrict__ Bt, void* __restrict__ C,
    int K, int lda, int ldb, int ldc,
    long aStride, long bStride, long cStride, float alpha) {
  int mt, nt;
  if (TRI) {
    const int bid = blockIdx.x;           // C(m) = m(m+1)/2; m+1 blocks per m
    int m = (int)((sqrtf(8.0f * (float)bid + 1.0f) - 1.0f) * 0.5f);
    while ((m + 1) * (m + 2) / 2 <= bid) ++m;
    while (m * (m + 1) / 2 > bid) --m;
    mt = m; nt = bid - m * (m + 1) / 2;
  } else { mt = blockIdx.x; nt = blockIdx.y; }
  const int bz = blockIdx.z;
  const int tid = threadIdx.x, wv = tid >> 6, ln = tid & 63;
  const int wm = wv & 1, wn = wv >> 1;            // 2 x 4 wave grid
  const int lr = ln & 15, quad = ln >> 4;
  const int swq = (quad ^ ((lr >> 1) & 3)) << 3;  // read-side swizzle (elems)
  const u16* Ag = A + (long)bz * aStride + (long)(mt * 256) * lda;
  const u16* Bg = Bt + (long)bz * bStride + (long)(nt * 256) * ldb;

  __shared__ __align__(16) __bf16 As[2][2][256 * 32];   // 64 KB
  __shared__ __align__(16) __bf16 Bs[2][2][256 * 32];   // 64 KB

  f32x4 acc[8][4];
#pragma unroll
  for (int i = 0; i < 8; ++i)
#pragma unroll
    for (int j = 0; j < 4; ++j)
#pragma unroll
      for (int r = 0; r < 4; ++r) acc[i][j][r] = 0.f;

  // staging: each half-slot = 256 rows x 32 k = 1024 16B-chunks; this thread
  // handles chunks c0=tid, c1=tid+512. chunk c -> row=c>>2, col8=c&3;
  // swizzled GLOBAL col = (col8 ^ ((row>>1)&3))*8; LDS dest linear (c*16B,
  // per-wave contiguous: base + lane*16, satisfying the HW dest rule).
  const int c0 = tid, c1 = tid + 512;
  const int r0 = c0 >> 2, r1 = c1 >> 2;
  const long a0 = (long)r0 * lda + (((c0 & 3) ^ ((r0 >> 1) & 3)) << 3);
  const long a1 = (long)r1 * lda + (((c1 & 3) ^ ((r1 >> 1) & 3)) << 3);
  const long b0 = (long)r0 * ldb + (((c0 & 3) ^ ((r0 >> 1) & 3)) << 3);
  const long b1 = (long)r1 * ldb + (((c1 & 3) ^ ((r1 >> 1) & 3)) << 3);
  const int l0 = c0 * 8, l1 = c1 * 8;   // LDS elem offsets

  const int kend = K;                    // requires K % 128 == 0, K >= 256

  // prologue: tile 0 -> buf 0 (4 half-slots), then vmcnt(4): oldest 4 ops
  // (A-kp0, B-kp0) landed; A-kp1/B-kp1 may still fly (guarded by P2 vmcnt).
  G8_STAGE_A(0, 0, 0); G8_STAGE_B(0, 0, 0);
  G8_STAGE_A(0, 1, 32); G8_STAGE_B(0, 1, 32);
  G8_VMC4(); G8_BAR();

  for (int k0 = 0; k0 < kend; k0 += 128) {
    const long kn0 = (k0 + 64  < kend) ? (long)k0 + 64  : (long)k0;       // -> buf1
    const long kn1 = (k0 + 128 < kend) ? (long)k0 + 128 : (long)k0 + 64;  // -> buf0
    G8_TILE(0, 1, k0, kn0);
    G8_TILE(1, 0, k0 + 64, kn1);
  }
  G8_VMC0();   // drain dead tail prefetches before block retire

  // epilogue: C/D layout col=lane&15, row=(lane>>4)*4+reg  [verified m89/m91]
  const long cb = (long)bz * cStride;
#pragma unroll
  for (int i = 0; i < 8; ++i) {
    int row0 = mt * 256 + wm * 128 + i * 16 + quad * 4;
#pragma unroll
    for (int j = 0; j < 4; ++j) {
      int col = nt * 256 + wn * 64 + j * 16 + lr;
#pragma unroll
      for (int r = 0; r < 4; ++r) {
        float v = acc[i][j][r] * alpha;
        long idx = cb + (long)(row0 + r) * ldc + col;
        if (OUTF32) ((float*)C)[idx] = v;
        else        ((u16*)C)[idx]  = f2bf(v);
      }
    }
  }
}

// ------------------------- 4-wave GEMM (PV only) ---------------------------
// C[m][n] = alpha * sum_k A[m][k] * Bt[n][k]; A,Bt bf16 row-major.
// Block tile BM(M) x 128(N), BK=64 as two BK=32 LDS panels.
// CK: causal PV, BM=128: balanced 1D grid, k-limit (mt+1)*128.
template <bool OUTF32, bool TRI, bool CK, int BM>
__global__ void __launch_bounds__(256, BM == 256 ? 2 : 4) gemm_bt(
    const u16* __restrict__ A, const u16* __restrict__ Bt, void* __restrict__ C,
    int K, int lda, int ldb, int ldc,
    long aStride, long bStride, long cStride, float alpha) {
  constexpr int MR = BM / 32;   // acc M-fragments per wave (8 or 4)
  constexpr int AQ = BM / 64;   // A staging chunks per thread per panel
  int mt, nt, bz;
  if (TRI) {
    const int bid = blockIdx.x;           // C(m) = m*(m+1); 2m+2 blocks per m
    int m = (int)((sqrtf(4.0f * (float)bid + 1.0f) - 1.0f) * 0.5f);
    while ((m + 1) * (m + 2) <= bid) ++m;
    while (m * (m + 1) > bid) --m;
    mt = m; nt = bid - m * (m + 1);
    bz = blockIdx.z;
  } else if (CK) {
    // 1024 blocks; buddies {c,c+256,c+512,c+768} (one CU under round-robin)
    // receive mts {31-g, 16+g, 15-g, g}: per-CU work == 66 units, constant.
    // Same-mt blocks sit at ids == const (mod 8) -> same XCD -> L2 A-reuse.
    const int id = blockIdx.x;
    const int g = id & 7, mid = (id >> 3) & 31, hi = id >> 8;
    bz = mid & 3; nt = mid >> 2;
    mt = (hi == 0) ? 31 - g : (hi == 1) ? 16 + g : (hi == 2) ? 15 - g : g;
  } else {
    mt = blockIdx.x; nt = blockIdx.y; bz = blockIdx.z;
  }
  const int tid = threadIdx.x, wv = tid >> 6, ln = tid & 63;
  const u16* Ag = A + (long)bz * aStride + (long)(mt * BM) * lda;
  const u16* Bg = Bt + (long)bz * bStride + (long)(nt * 128) * ldb;

  __shared__ __align__(16) __bf16 As[2][BM * 32];
  __shared__ __align__(16) __bf16 Bs[2][128 * 32];

  f32x4 acc[MR][4];
#pragma unroll
  for (int i = 0; i < MR; ++i)
#pragma unroll
    for (int j = 0; j < 4; ++j)
#pragma unroll
      for (int r = 0; r < 4; ++r) acc[i][j][r] = 0.f;

  const int kend = CK ? (((mt + 1) * BM < K) ? (mt + 1) * BM : K) : K;
  const int wm = wv & 1, wn = wv >> 1;
  const int mrow = wm * (BM / 2), nrow = wn * 64;
  const int lr = ln & 15, quad = ln >> 4;

  long aOff[AQ]; int aLds[AQ];
#pragma unroll
  for (int q = 0; q < AQ; ++q) {
    int c = q * 256 + tid, row = c >> 2, c8i = c & 3;
    aOff[q] = (long)row * lda + ((c8i ^ ((row >> 1) & 3)) << 3);
    aLds[q] = c * 8;                       // elements
  }
  long bOff[2]; int bLds[2];
#pragma unroll
  for (int q = 0; q < 2; ++q) {
    int c = q * 256 + tid, row = c >> 2, c8i = c & 3;
    bOff[q] = (long)row * ldb + ((c8i ^ ((row >> 1) & 3)) << 3);
    bLds[q] = c * 8;
  }
  const int swq = (quad ^ ((lr >> 1) & 3)) << 3;

  for (int k0 = 0; k0 < kend; k0 += 64) {
#pragma unroll
    for (int p = 0; p < 2; ++p) {
      const long kk = k0 + p * 32;
#pragma unroll
      for (int q = 0; q < AQ; ++q)
        async16(Ag + kk + aOff[q], (char*)As[p] + aLds[q] * 2);
#pragma unroll
      for (int q = 0; q < 2; ++q)
        async16(Bg + kk + bOff[q], (char*)Bs[p] + bLds[q] * 2);
    }
    __syncthreads();   // drains vmcnt before barrier
#pragma unroll
    for (int p = 0; p < 2; ++p) {
      bf16x8 af[MR], bfr[4];
#pragma unroll
      for (int u = 0; u < MR; ++u)
        af[u] = *(const bf16x8*)&As[p][(mrow + u * 16 + lr) * 32 + swq];
#pragma unroll
      for (int j = 0; j < 4; ++j)
        bfr[j] = *(const bf16x8*)&Bs[p][(nrow + j * 16 + lr) * 32 + swq];
#pragma unroll
      for (int u = 0; u < MR; ++u)
#pragma unroll
        for (int j = 0; j < 4; ++j)
          acc[u][j] = __builtin_amdgcn_mfma_f32_16x16x32_bf16(af[u], bfr[j], acc[u][j], 0, 0, 0);
    }
    __syncthreads();   // protect LDS before next refill
  }

  const long cb = (long)bz * cStride;
#pragma unroll
  for (int i = 0; i < MR; ++i) {
    int row0 = mt * BM + mrow + i * 16 + quad * 4;
#pragma unroll
    for (int j = 0; j < 4; ++j) {
      int col = nt * 128 + nrow + j * 16 + lr;
#pragma unroll
      for (int r = 0; r < 4; ++r) {
        float v = acc[i][j][r] * alpha;
        long idx = cb + (long)(row0 + r) * ldc + col;
        if (OUTF32) ((float*)C)[idx] = v;
        else        ((u16*)C)[idx]  = f2bf(v);
      }
    }
  }
}

// ------------------------------ row softmax --------------------------------
// One block per (row, batch). Pads [L, ceil256(L)) with zeros so the PV GEMM
// (128-row M-tiles, kend=(mt+1)*128 <= ceil256(row+1)) reads no garbage.
__global__ void __launch_bounds__(256) softmax_rows(u16* __restrict__ Sb,
                                                    long bStride, int S) {
  const int row = blockIdx.x;
  u16* p = Sb + (long)blockIdx.y * bStride + (long)row * S;
  const int L = row + 1;
  const int Lpad = (L + 255) & ~255;
  const int tid = threadIdx.x, ln = tid & 63, wv = tid >> 6;
  __shared__ float red[8];

  float vals[16];
  float lmax = -3.4e38f;
#pragma unroll
  for (int k = 0; k < 16; ++k) {
    int j = tid + k * 256;
    if (j < L) { float v = bf2f(p[j]); vals[k] = v; lmax = fmaxf(lmax, v); }
  }
#pragma unroll
  for (int o = 32; o > 0; o >>= 1) lmax = fmaxf(lmax, __shfl_down(lmax, o));
  if (ln == 0) red[wv] = lmax;
  __syncthreads();
  float m = fmaxf(fmaxf(red[0], red[1]), fmaxf(red[2], red[3]));

  float lsum = 0.f;
#pragma unroll
  for (int k = 0; k < 16; ++k) {
    int j = tid + k * 256;
    if (j < L) { float e = __expf(vals[k] - m); vals[k] = e; lsum += e; }
  }
#pragma unroll
  for (int o = 32; o > 0; o >>= 1) lsum += __shfl_down(lsum, o);
  __syncthreads();
  if (ln == 0) red[wv] = lsum;
  __syncthreads();
  float inv = 1.f / (red[0] + red[1] + red[2] + red[3]);
#pragma unroll
  for (int k = 0; k < 16; ++k) {
    int j = tid + k * 256;
    if (j < L) p[j] = f2bf(vals[k] * inv);
  }
  for (int j = L + tid; j < Lpad; j += 256) p[j] = 0;
}

// ------------------------------- launcher ----------------------------------
extern "C" void kernel_launch(void* const* d_in, const int* in_sizes, int n_in,
                              void* d_out, int out_size, void* d_ws, size_t ws_size,
                              hipStream_t stream) {
  const float* x = (const float*)d_in[0];
  const float* Q = (const float*)d_in[1];
  const float* K = (const float*)d_in[2];
  const float* V = (const float*)d_in[3];
  float* out = (float*)d_out;

  constexpr int  Bb = 4, S = 4096, D = 1024;
  constexpr long MB = 1024 * 1024;
  if (ws_size < (size_t)(224 * MB)) return;

  char* ws = (char*)d_ws;
  u16* QKx  = (u16*)(ws);             // [B*S][2048]  Qx=+0, Kx=+1024
  u16* Vxt  = (u16*)(ws + 64 * MB);   // [B][D][S]
  u16* Sb   = (u16*)(ws + 96 * MB);   // [B][S][S]
  u16* Vtmp = (u16*)(ws + 96 * MB);   // [B][S][D]   (dead before Sb written)
  u16* XB   = (u16*)(ws + 128 * MB);  // x bf16      (dead before Sb written)
  u16* WTqk = (u16*)(ws + 160 * MB);  // [2048][1024]
  u16* WTv  = (u16*)(ws + 164 * MB);  // [1024][1024]

  const long SD = (long)S * D, SS = (long)S * S;

  // 1. x -> bf16
  cvt_f32_bf16<<<dim3((Bb * S * D / 4) / 256), 256, 0, stream>>>(
      (const float4*)x, XB, Bb * S * D / 4);

  // 2. weight transposes (fp32 [k][n] -> bf16 [n][k]); 1/32 folded into Qt
  transpose_to_bf16<float><<<dim3(16, 16, 1), 256, 0, stream>>>(
      Q, WTqk, 1024, 1024, 0, 0, 0.03125f);
  transpose_to_bf16<float><<<dim3(16, 16, 1), 256, 0, stream>>>(
      K, WTqk + 1024 * 1024, 1024, 1024, 0, 0, 1.0f);
  transpose_to_bf16<float><<<dim3(16, 16, 1), 256, 0, stream>>>(
      V, WTv, 1024, 1024, 0, 0, 1.0f);

  // 3a. fused Q,K projection -> QKx [B*S][2048]  (64 x 8 = 512 blocks, 2 rounds)
  gemm8_bt<false, false><<<dim3(64, 8, 1), 512, 0, stream>>>(
      XB, WTqk, QKx, 1024, 1024, 1024, 2048, 0, 0, 0, 1.0f);
  // 3b. V projection -> Vtmp  (64 x 4 = 256 blocks, 1 round)
  gemm8_bt<false, false><<<dim3(64, 4, 1), 512, 0, stream>>>(
      XB, WTv, Vtmp, 1024, 1024, 1024, 1024, 0, 0, 0, 1.0f);

  // 4. Vtmp [b][s][d] -> Vxt [b][d][s]
  transpose_to_bf16<u16><<<dim3(64, 16, Bb), 256, 0, stream>>>(
      Vtmp, Vxt, S, D, SD, SD, 1.0f);

  // 5. causal scores: Sb = Qx @ Kx^T, TRI 256^2 grid (16 m-tiles, n<=m:
  //    136 blocks/batch). QKx batch stride = S*2048 = 2*SD.
  gemm8_bt<false, true><<<dim3(136, 1, Bb), 512, 0, stream>>>(
      QKx, QKx + 1024, Sb, 1024, 2048, 2048, S, 2 * SD, 2 * SD, SS, 1.0f);

  // 6. row softmax in place (zero-pads rows to 256 boundary)
  softmax_rows<<<dim3(S, Bb), 256, 0, stream>>>(Sb, SS, S);

  // 7. out = P @ Vxt^T (causal k-limit; balanced 1D grid, 1024 blocks of
  //    128x128; batch/nt/mt decoded in-kernel)
  gemm_bt<true, false, true, 128><<<dim3(1024, 1, 1), 256, 0, stream>>>(
      Sb, Vxt, out, S, S, S, D, SS, SD, SD, 1.0f);
}

// Round 4
// 475.419 us; speedup vs baseline: 1.0635x; 1.0635x over previous
//
#include <hip/hip_runtime.h>
#include <cstdint>
#include <cstddef>
#include <cmath>

// ---------------------------------------------------------------------------
// DotProductAttention: out = softmax_causal((x@Q/32) @ (x@K)^T) @ (x@V)
//   B=4, S=4096, D=1024, fp32 in/out, bf16 MFMA compute.
// R9 changes vs R8 (505 us):
//   - Post-mortem: QK^T's 110 us == 3-round makespan of 544 equal blocks at
//     1 block/CU -> per-block ~950 TF; the 8-phase gain was eaten by the
//     forced ceil(544/256)=3 quantization (2.125/3 = 71% packing). GEMMs are
//     at their structural floor; the overlooked cost is the scalar-bf16
//     small kernels (~95 us): softmax (scalar u16, ~55) + V transpose (~40).
//   - softmax_rows vectorized: 2x u16x8 per thread (16B/lane coalesced),
//     validity-masked, zero-pad folded into the vectorized store.
//   - V transpose ELIMINATED: projV now computes Vxt[d][b*S+s] directly as
//     C[m=d][n=bs] = sum_k WTv[d][k]*XB[bs][k] (gemm8, 4x64=256 blocks =
//     exactly 1 round, K=1024). PV reads it with ldb=16384, bStride=4096.
//     Bit-identical numerics; Vtmp buffer and transpose dispatch gone.
//   - gemm8_bt (R8): 256x256 tile, 512 thr (8 waves 2Mx4N, wave 128x64),
//     128 KB LDS, 8-phase counted-vmcnt schedule (T3+T4+T5), zero-conflict
//     XOR swizzle. PV keeps R6 balanced 4-wave BM=128 kernel.
// Workspace map (224 MB):
//   [0,64)   QKx bf16 [B*S][2048]  (Qx=+0, Kx=+1024, ld 2048)
//   [64,96)  Vxt bf16 [D][B*S] = [1024][16384]
//   [96,224) Sb bf16 [B][S][S]  -- early-phase reuse (all dead before Sb):
//       XB@128 (32M), WTqk@160 (4M), WTv@164 (2M)
// ---------------------------------------------------------------------------

typedef unsigned short u16;
typedef __bf16  bf16x8 __attribute__((ext_vector_type(8)));
typedef float   f32x4  __attribute__((ext_vector_type(4)));
typedef unsigned short u16x4 __attribute__((ext_vector_type(4)));
typedef unsigned short u16x8 __attribute__((ext_vector_type(8)));

typedef __attribute__((address_space(1))) void gvoid;
typedef __attribute__((address_space(3))) void lvoid;

__device__ __forceinline__ u16 f2bf(float f) {
  union { float f; unsigned u; } v; v.f = f;
  unsigned u = v.u;
  u += 0x7FFFu + ((u >> 16) & 1u);   // round-to-nearest-even
  return (u16)(u >> 16);
}
__device__ __forceinline__ float bf2f(u16 h) {
  union { unsigned u; float f; } v; v.u = ((unsigned)h) << 16;
  return v.f;
}
__device__ __forceinline__ void async16(const void* g, void* l) {
  __builtin_amdgcn_global_load_lds((gvoid*)(void*)g, (lvoid*)l, 16, 0, 0);
}

// --------------------------- elementwise convert ---------------------------
__global__ void __launch_bounds__(256) cvt_f32_bf16(const float4* __restrict__ in,
                                                    u16* __restrict__ out, int n4) {
  int i = blockIdx.x * 256 + threadIdx.x;
  if (i >= n4) return;
  float4 v = in[i];
  u16x4 o = { f2bf(v.x), f2bf(v.y), f2bf(v.z), f2bf(v.w) };
  *(u16x4*)(out + 4 * (size_t)i) = o;
}

// ------------------------- transpose (weights only) ------------------------
template <typename TIN>
__global__ void __launch_bounds__(256) transpose_to_bf16(
    const TIN* __restrict__ in, u16* __restrict__ out,
    int rows, int cols, long inStride, long outStride, float scale) {
  __shared__ u16 t[64][68];                 // stride 136B -> 2-way alias (free)
  int rt = blockIdx.x * 64, ct = blockIdx.y * 64;
  long ib = (long)blockIdx.z * inStride, ob = (long)blockIdx.z * outStride;
  int tx = threadIdx.x & 63, ty = threadIdx.x >> 6;
#pragma unroll
  for (int r = ty; r < 64; r += 4)
    t[r][tx] = f2bf((float)in[ib + (long)(rt + r) * cols + ct + tx] * scale);
  __syncthreads();
#pragma unroll
  for (int r = ty; r < 64; r += 4)
    out[ob + (long)(ct + r) * rows + rt + tx] = t[tx][r];
}

// --------------------- 8-phase 256x256 GEMM (gemm8_bt) ---------------------
// C[m][n] = alpha * sum_k A[m][k]*Bt[n][k]; bf16 row-major; K mult of 128.
// 512 threads = 8 waves (2M x 4N); wave tile 128x64; acc[8][4] 16x16x32.
// LDS: As/Bs[2 buf][2 kp][256 rows][32 k] = 128 KB total, 1 block/CU.
// TRI: full-tile lower-triangle grid, bid -> (m, n<=m), C(m)=m(m+1)/2.

#define G8_BAR()  __builtin_amdgcn_s_barrier()
#define G8_VMC4() asm volatile("s_waitcnt vmcnt(4)" ::: "memory")
#define G8_VMC0() asm volatile("s_waitcnt vmcnt(0)" ::: "memory")

#define G8_STAGE_A(bn, kp, kb) do { \
    async16(Ag + (kb) + a0, (void*)&As[bn][kp][l0]); \
    async16(Ag + (kb) + a1, (void*)&As[bn][kp][l1]); } while (0)
#define G8_STAGE_B(bn, kp, kb) do { \
    async16(Bg + (kb) + b0, (void*)&Bs[bn][kp][l0]); \
    async16(Bg + (kb) + b1, (void*)&Bs[bn][kp][l1]); } while (0)

#define G8_LDA(bc, kp, ch) do { _Pragma("unroll") \
    for (int u_ = 0; u_ < 4; ++u_) \
      af[u_] = *(const bf16x8*)&As[bc][kp][(wm * 128 + (ch) * 64 + u_ * 16 + lr) * 32 + swq]; \
  } while (0)
#define G8_LDB(bc, kp) do { _Pragma("unroll") \
    for (int j_ = 0; j_ < 4; ++j_) \
      bf[j_] = *(const bf16x8*)&Bs[bc][kp][(wn * 64 + j_ * 16 + lr) * 32 + swq]; \
  } while (0)

#define G8_MFMA(ch) do { \
    __builtin_amdgcn_s_setprio(1); \
    _Pragma("unroll") for (int u_ = 0; u_ < 4; ++u_) \
      _Pragma("unroll") for (int j_ = 0; j_ < 4; ++j_) \
        acc[(ch) * 4 + u_][j_] = __builtin_amdgcn_mfma_f32_16x16x32_bf16( \
            af[u_], bf[j_], acc[(ch) * 4 + u_][j_], 0, 0, 0); \
    __builtin_amdgcn_s_setprio(0); } while (0)

// one K-tile (64) from buffer bc; prefetch next tile's half-slots into bn
#define G8_TILE(bc, bn, kt, kn) do { \
    bf16x8 af[4], bf[4]; \
    /* P1: kp0, C rows 0-63 */ \
    G8_LDB(bc, 0); G8_LDA(bc, 0, 0); \
    G8_STAGE_A(bn, 0, (kn)); \
    G8_BAR(); G8_MFMA(0); G8_BAR(); \
    /* P2: kp0, C rows 64-127 */ \
    G8_LDA(bc, 0, 1); \
    G8_STAGE_B(bn, 0, (kn)); \
    G8_BAR(); G8_MFMA(1); G8_VMC4(); G8_BAR(); \
    /* P3: kp1, C rows 0-63 */ \
    G8_LDB(bc, 1); G8_LDA(bc, 1, 0); \
    G8_STAGE_A(bn, 1, (kn) + 32); \
    G8_BAR(); G8_MFMA(0); G8_BAR(); \
    /* P4: kp1, C rows 64-127 */ \
    G8_LDA(bc, 1, 1); \
    G8_STAGE_B(bn, 1, (kn) + 32); \
    G8_BAR(); G8_MFMA(1); G8_VMC4(); G8_BAR(); } while (0)

template <bool OUTF32, bool TRI>
__global__ void __launch_bounds__(512, 2) gemm8_bt(
    const u16* __restrict__ A, const u16* __restrict__ Bt, void* __restrict__ C,
    int K, int lda, int ldb, int ldc,
    long aStride, long bStride, long cStride, float alpha) {
  int mt, nt;
  if (TRI) {
    const int bid = blockIdx.x;           // C(m) = m(m+1)/2; m+1 blocks per m
    int m = (int)((sqrtf(8.0f * (float)bid + 1.0f) - 1.0f) * 0.5f);
    while ((m + 1) * (m + 2) / 2 <= bid) ++m;
    while (m * (m + 1) / 2 > bid) --m;
    mt = m; nt = bid - m * (m + 1) / 2;
  } else { mt = blockIdx.x; nt = blockIdx.y; }
  const int bz = blockIdx.z;
  const int tid = threadIdx.x, wv = tid >> 6, ln = tid & 63;
  const int wm = wv & 1, wn = wv >> 1;            // 2 x 4 wave grid
  const int lr = ln & 15, quad = ln >> 4;
  const int swq = (quad ^ ((lr >> 1) & 3)) << 3;  // read-side swizzle (elems)
  const u16* Ag = A + (long)bz * aStride + (long)(mt * 256) * lda;
  const u16* Bg = Bt + (long)bz * bStride + (long)(nt * 256) * ldb;

  __shared__ __align__(16) __bf16 As[2][2][256 * 32];   // 64 KB
  __shared__ __align__(16) __bf16 Bs[2][2][256 * 32];   // 64 KB

  f32x4 acc[8][4];
#pragma unroll
  for (int i = 0; i < 8; ++i)
#pragma unroll
    for (int j = 0; j < 4; ++j)
#pragma unroll
      for (int r = 0; r < 4; ++r) acc[i][j][r] = 0.f;

  // staging: each half-slot = 256 rows x 32 k = 1024 16B-chunks; this thread
  // handles chunks c0=tid, c1=tid+512. chunk c -> row=c>>2, col8=c&3;
  // swizzled GLOBAL col = (col8 ^ ((row>>1)&3))*8; LDS dest linear (c*16B,
  // per-wave contiguous: base + lane*16, satisfying the HW dest rule).
  const int c0 = tid, c1 = tid + 512;
  const int r0 = c0 >> 2, r1 = c1 >> 2;
  const long a0 = (long)r0 * lda + (((c0 & 3) ^ ((r0 >> 1) & 3)) << 3);
  const long a1 = (long)r1 * lda + (((c1 & 3) ^ ((r1 >> 1) & 3)) << 3);
  const long b0 = (long)r0 * ldb + (((c0 & 3) ^ ((r0 >> 1) & 3)) << 3);
  const long b1 = (long)r1 * ldb + (((c1 & 3) ^ ((r1 >> 1) & 3)) << 3);
  const int l0 = c0 * 8, l1 = c1 * 8;   // LDS elem offsets

  const int kend = K;                    // requires K % 128 == 0, K >= 256

  // prologue: tile 0 -> buf 0 (4 half-slots), then vmcnt(4): oldest 4 ops
  // (A-kp0, B-kp0) landed; A-kp1/B-kp1 may still fly (guarded by P2 vmcnt).
  G8_STAGE_A(0, 0, 0); G8_STAGE_B(0, 0, 0);
  G8_STAGE_A(0, 1, 32); G8_STAGE_B(0, 1, 32);
  G8_VMC4(); G8_BAR();

  for (int k0 = 0; k0 < kend; k0 += 128) {
    const long kn0 = (k0 + 64  < kend) ? (long)k0 + 64  : (long)k0;       // -> buf1
    const long kn1 = (k0 + 128 < kend) ? (long)k0 + 128 : (long)k0 + 64;  // -> buf0
    G8_TILE(0, 1, k0, kn0);
    G8_TILE(1, 0, k0 + 64, kn1);
  }
  G8_VMC0();   // drain dead tail prefetches before block retire

  // epilogue: C/D layout col=lane&15, row=(lane>>4)*4+reg  [verified m89/m91]
  const long cb = (long)bz * cStride;
#pragma unroll
  for (int i = 0; i < 8; ++i) {
    int row0 = mt * 256 + wm * 128 + i * 16 + quad * 4;
#pragma unroll
    for (int j = 0; j < 4; ++j) {
      int col = nt * 256 + wn * 64 + j * 16 + lr;
#pragma unroll
      for (int r = 0; r < 4; ++r) {
        float v = acc[i][j][r] * alpha;
        long idx = cb + (long)(row0 + r) * ldc + col;
        if (OUTF32) ((float*)C)[idx] = v;
        else        ((u16*)C)[idx]  = f2bf(v);
      }
    }
  }
}

// ------------------------- 4-wave GEMM (PV only) ---------------------------
// C[m][n] = alpha * sum_k A[m][k] * Bt[n][k]; A,Bt bf16 row-major.
// Block tile BM(M) x 128(N), BK=64 as two BK=32 LDS panels.
// CK: causal PV, BM=128: balanced 1D grid, k-limit (mt+1)*128.
template <bool OUTF32, bool TRI, bool CK, int BM>
__global__ void __launch_bounds__(256, BM == 256 ? 2 : 4) gemm_bt(
    const u16* __restrict__ A, const u16* __restrict__ Bt, void* __restrict__ C,
    int K, int lda, int ldb, int ldc,
    long aStride, long bStride, long cStride, float alpha) {
  constexpr int MR = BM / 32;   // acc M-fragments per wave (8 or 4)
  constexpr int AQ = BM / 64;   // A staging chunks per thread per panel
  int mt, nt, bz;
  if (TRI) {
    const int bid = blockIdx.x;           // C(m) = m*(m+1); 2m+2 blocks per m
    int m = (int)((sqrtf(4.0f * (float)bid + 1.0f) - 1.0f) * 0.5f);
    while ((m + 1) * (m + 2) <= bid) ++m;
    while (m * (m + 1) > bid) --m;
    mt = m; nt = bid - m * (m + 1);
    bz = blockIdx.z;
  } else if (CK) {
    // 1024 blocks; buddies {c,c+256,c+512,c+768} (one CU under round-robin)
    // receive mts {31-g, 16+g, 15-g, g}: per-CU work == 66 units, constant.
    // Same-mt blocks sit at ids == const (mod 8) -> same XCD -> L2 A-reuse.
    const int id = blockIdx.x;
    const int g = id & 7, mid = (id >> 3) & 31, hi = id >> 8;
    bz = mid & 3; nt = mid >> 2;
    mt = (hi == 0) ? 31 - g : (hi == 1) ? 16 + g : (hi == 2) ? 15 - g : g;
  } else {
    mt = blockIdx.x; nt = blockIdx.y; bz = blockIdx.z;
  }
  const int tid = threadIdx.x, wv = tid >> 6, ln = tid & 63;
  const u16* Ag = A + (long)bz * aStride + (long)(mt * BM) * lda;
  const u16* Bg = Bt + (long)bz * bStride + (long)(nt * 128) * ldb;

  __shared__ __align__(16) __bf16 As[2][BM * 32];
  __shared__ __align__(16) __bf16 Bs[2][128 * 32];

  f32x4 acc[MR][4];
#pragma unroll
  for (int i = 0; i < MR; ++i)
#pragma unroll
    for (int j = 0; j < 4; ++j)
#pragma unroll
      for (int r = 0; r < 4; ++r) acc[i][j][r] = 0.f;

  const int kend = CK ? (((mt + 1) * BM < K) ? (mt + 1) * BM : K) : K;
  const int wm = wv & 1, wn = wv >> 1;
  const int mrow = wm * (BM / 2), nrow = wn * 64;
  const int lr = ln & 15, quad = ln >> 4;

  long aOff[AQ]; int aLds[AQ];
#pragma unroll
  for (int q = 0; q < AQ; ++q) {
    int c = q * 256 + tid, row = c >> 2, c8i = c & 3;
    aOff[q] = (long)row * lda + ((c8i ^ ((row >> 1) & 3)) << 3);
    aLds[q] = c * 8;                       // elements
  }
  long bOff[2]; int bLds[2];
#pragma unroll
  for (int q = 0; q < 2; ++q) {
    int c = q * 256 + tid, row = c >> 2, c8i = c & 3;
    bOff[q] = (long)row * ldb + ((c8i ^ ((row >> 1) & 3)) << 3);
    bLds[q] = c * 8;
  }
  const int swq = (quad ^ ((lr >> 1) & 3)) << 3;

  for (int k0 = 0; k0 < kend; k0 += 64) {
#pragma unroll
    for (int p = 0; p < 2; ++p) {
      const long kk = k0 + p * 32;
#pragma unroll
      for (int q = 0; q < AQ; ++q)
        async16(Ag + kk + aOff[q], (char*)As[p] + aLds[q] * 2);
#pragma unroll
      for (int q = 0; q < 2; ++q)
        async16(Bg + kk + bOff[q], (char*)Bs[p] + bLds[q] * 2);
    }
    __syncthreads();   // drains vmcnt before barrier
#pragma unroll
    for (int p = 0; p < 2; ++p) {
      bf16x8 af[MR], bfr[4];
#pragma unroll
      for (int u = 0; u < MR; ++u)
        af[u] = *(const bf16x8*)&As[p][(mrow + u * 16 + lr) * 32 + swq];
#pragma unroll
      for (int j = 0; j < 4; ++j)
        bfr[j] = *(const bf16x8*)&Bs[p][(nrow + j * 16 + lr) * 32 + swq];
#pragma unroll
      for (int u = 0; u < MR; ++u)
#pragma unroll
        for (int j = 0; j < 4; ++j)
          acc[u][j] = __builtin_amdgcn_mfma_f32_16x16x32_bf16(af[u], bfr[j], acc[u][j], 0, 0, 0);
    }
    __syncthreads();   // protect LDS before next refill
  }

  const long cb = (long)bz * cStride;
#pragma unroll
  for (int i = 0; i < MR; ++i) {
    int row0 = mt * BM + mrow + i * 16 + quad * 4;
#pragma unroll
    for (int j = 0; j < 4; ++j) {
      int col = nt * 128 + nrow + j * 16 + lr;
#pragma unroll
      for (int r = 0; r < 4; ++r) {
        float v = acc[i][j][r] * alpha;
        long idx = cb + (long)(row0 + r) * ldc + col;
        if (OUTF32) ((float*)C)[idx] = v;
        else        ((u16*)C)[idx]  = f2bf(v);
      }
    }
  }
}

// ------------------------------ row softmax --------------------------------
// One block per (row, batch). Vectorized u16x8 (16B/lane); zero-pads
// [L, ceil256(L)) via the same vectorized stores so the PV GEMM
// (128-row M-tiles, kend=(mt+1)*128 <= ceil256(row+1)) reads no garbage.
__global__ void __launch_bounds__(256) softmax_rows(u16* __restrict__ Sb,
                                                    long bStride, int S) {
  const int row = blockIdx.x;
  u16* p = Sb + (long)blockIdx.y * bStride + (long)row * S;
  const int L = row + 1;
  const int Lpad = (L + 255) & ~255;
  const int tid = threadIdx.x, ln = tid & 63, wv = tid >> 6;
  const int base0 = tid * 16;               // 256 thr x 16 elems == 4096
  __shared__ float red[4];

  float vals[16];
  float lmax = -3.4e38f;
#pragma unroll
  for (int k = 0; k < 2; ++k) {
    const int b = base0 + k * 8;
    if (b < L) {
      u16x8 v = *(const u16x8*)(p + b);
#pragma unroll
      for (int e = 0; e < 8; ++e) {
        if (b + e < L) { float f = bf2f(v[e]); vals[k * 8 + e] = f; lmax = fmaxf(lmax, f); }
        else vals[k * 8 + e] = 0.f;
      }
    } else {
#pragma unroll
      for (int e = 0; e < 8; ++e) vals[k * 8 + e] = 0.f;
    }
  }
#pragma unroll
  for (int o = 32; o > 0; o >>= 1) lmax = fmaxf(lmax, __shfl_down(lmax, o));
  if (ln == 0) red[wv] = lmax;
  __syncthreads();
  float m = fmaxf(fmaxf(red[0], red[1]), fmaxf(red[2], red[3]));

  float lsum = 0.f;
#pragma unroll
  for (int k = 0; k < 2; ++k) {
    const int b = base0 + k * 8;
#pragma unroll
    for (int e = 0; e < 8; ++e) {
      float ex = (b + e < L) ? __expf(vals[k * 8 + e] - m) : 0.f;
      vals[k * 8 + e] = ex; lsum += ex;
    }
  }
#pragma unroll
  for (int o = 32; o > 0; o >>= 1) lsum += __shfl_down(lsum, o);
  __syncthreads();
  if (ln == 0) red[wv] = lsum;
  __syncthreads();
  float inv = 1.f / (red[0] + red[1] + red[2] + red[3]);
#pragma unroll
  for (int k = 0; k < 2; ++k) {
    const int b = base0 + k * 8;
    if (b < Lpad) {                         // stores zeros for [L, Lpad)
      u16x8 o;
#pragma unroll
      for (int e = 0; e < 8; ++e) o[e] = f2bf(vals[k * 8 + e] * inv);
      *(u16x8*)(p + b) = o;
    }
  }
}

// ------------------------------- launcher ----------------------------------
extern "C" void kernel_launch(void* const* d_in, const int* in_sizes, int n_in,
                              void* d_out, int out_size, void* d_ws, size_t ws_size,
                              hipStream_t stream) {
  const float* x = (const float*)d_in[0];
  const float* Q = (const float*)d_in[1];
  const float* K = (const float*)d_in[2];
  const float* V = (const float*)d_in[3];
  float* out = (float*)d_out;

  constexpr int  Bb = 4, S = 4096, D = 1024;
  constexpr long MB = 1024 * 1024;
  if (ws_size < (size_t)(224 * MB)) return;

  char* ws = (char*)d_ws;
  u16* QKx  = (u16*)(ws);             // [B*S][2048]  Qx=+0, Kx=+1024
  u16* Vxt  = (u16*)(ws + 64 * MB);   // [D][B*S] = [1024][16384]
  u16* Sb   = (u16*)(ws + 96 * MB);   // [B][S][S]
  u16* XB   = (u16*)(ws + 128 * MB);  // x bf16      (dead before Sb written)
  u16* WTqk = (u16*)(ws + 160 * MB);  // [2048][1024]
  u16* WTv  = (u16*)(ws + 164 * MB);  // [1024][1024]

  const long SD = (long)S * D, SS = (long)S * S;

  // 1. x -> bf16
  cvt_f32_bf16<<<dim3((Bb * S * D / 4) / 256), 256, 0, stream>>>(
      (const float4*)x, XB, Bb * S * D / 4);

  // 2. weight transposes (fp32 [k][n] -> bf16 [n][k]); 1/32 folded into Qt
  transpose_to_bf16<float><<<dim3(16, 16, 1), 256, 0, stream>>>(
      Q, WTqk, 1024, 1024, 0, 0, 0.03125f);
  transpose_to_bf16<float><<<dim3(16, 16, 1), 256, 0, stream>>>(
      K, WTqk + 1024 * 1024, 1024, 1024, 0, 0, 1.0f);
  transpose_to_bf16<float><<<dim3(16, 16, 1), 256, 0, stream>>>(
      V, WTv, 1024, 1024, 0, 0, 1.0f);

  // 3a. fused Q,K projection -> QKx [B*S][2048]  (64 x 8 = 512 blocks, 2 rounds)
  gemm8_bt<false, false><<<dim3(64, 8, 1), 512, 0, stream>>>(
      XB, WTqk, QKx, 1024, 1024, 1024, 2048, 0, 0, 0, 1.0f);
  // 3b. V projection written TRANSPOSED: Vxt[d][b*S+s] = (x@V)[b,s,d]
  //     C[m=d][n=bs] = sum_k WTv[d][k]*XB[bs][k]; 4x64 = 256 blocks, 1 round.
  gemm8_bt<false, false><<<dim3(4, 64, 1), 512, 0, stream>>>(
      WTv, XB, Vxt, 1024, 1024, 1024, 16384, 0, 0, 0, 1.0f);

  // 4. causal scores: Sb = Qx @ Kx^T, TRI 256^2 grid (16 m-tiles, n<=m:
  //    136 blocks/batch). QKx batch stride = S*2048 = 2*SD.
  gemm8_bt<false, true><<<dim3(136, 1, Bb), 512, 0, stream>>>(
      QKx, QKx + 1024, Sb, 1024, 2048, 2048, S, 2 * SD, 2 * SD, SS, 1.0f);

  // 5. row softmax in place (vectorized; zero-pads rows to 256 boundary)
  softmax_rows<<<dim3(S, Bb), 256, 0, stream>>>(Sb, SS, S);

  // 6. out = P @ Vxt (causal k-limit; balanced 1D grid, 1024 blocks of
  //    128x128; batch/nt/mt decoded in-kernel). Vxt rows are d (ldb=16384),
  //    batch offset = b*4096 within a row.
  gemm_bt<true, false, true, 128><<<dim3(1024, 1, 1), 256, 0, stream>>>(
      Sb, Vxt, out, S, S, 16384, D, SS, 4096, SD, 1.0f);
}